// Round 3
// baseline (2683.612 us; speedup 1.0000x reference)
//
#include <hip/hip_runtime.h>
#include <hip/hip_bf16.h>

typedef __hip_bfloat16 bf16;

#define NB_B 4
#define N 20000
#define E 640000
#define F 64
#define HC 128   // conv1 heads*ch
#define ED 16
#define CH 16
#define EPB1 16
#define EPB2 16

__device__ __forceinline__ float b2f(bf16 v){ return __bfloat162float(v); }
__device__ __forceinline__ float clampf(float v, float lo, float hi){ return fminf(fmaxf(v, lo), hi); }
// dtype-generic load/store
__device__ __forceinline__ float ldv(const float* p, size_t i){ return p[i]; }
__device__ __forceinline__ float ldv(const bf16*  p, size_t i){ return __bfloat162float(p[i]); }
__device__ __forceinline__ void  stv(float* p, size_t i, float v){ p[i] = v; }
__device__ __forceinline__ void  stv(bf16*  p, size_t i, float v){ p[i] = __float2bfloat16(v); }

// ---------------- dtype detector: are inputs f32 (flag=1) or bf16 (flag=0)? ----------------
// If x is f32, its low-half 16-bit words reinterpreted as bf16 have uniform-random
// exponents -> mostly outside [1e-4,1e4]. If x is bf16, x[2*tid] is a genuine ~N(0,1) value.
__global__ __launch_bounds__(256) void k_detect(const unsigned short* __restrict__ xu, int* __restrict__ flag){
  __shared__ int cnt[256];
  int tid = threadIdx.x;
  unsigned short lo = xu[2*tid];
  bf16 h = *(const bf16*)&lo;
  float v = fabsf(__bfloat162float(h));
  int weird = (v > 1e4f || (v != 0.f && v < 1e-4f)) ? 1 : 0;
  cnt[tid] = weird;
  __syncthreads();
  for (int s=128; s>0; s>>=1){ if (tid<s) cnt[tid]+=cnt[tid+s]; __syncthreads(); }
  if (tid==0) *flag = (cnt[0] > 64) ? 1 : 0;
}

// ---------------- conv1 node transform: xl1/xr1 = x @ Wl / Wr (f32 out) ----------------
template<typename T>
__device__ __forceinline__ void node1_body(const T* x, const T* Wl, const T* Wr,
                                           float* xl1, float* xr1, int b0){
  int z = blockIdx.z, b = b0 + z;
  int nl = threadIdx.x >> 7;
  int c  = threadIdx.x & 127;
  int node = blockIdx.x*2 + nl;
  __shared__ float xs[2][F];
  for (int i=threadIdx.x; i<2*F; i+=256)
    xs[i>>6][i&63] = ldv(x, ((size_t)b*N + blockIdx.x*2 + (i>>6))*F + (i&63));
  __syncthreads();
  float al=0.f, ar=0.f;
  #pragma unroll 8
  for (int k=0;k<F;k++){
    float xv = xs[nl][k];
    al += xv * ldv(Wl, (size_t)k*HC+c);
    ar += xv * ldv(Wr, (size_t)k*HC+c);
  }
  size_t o = ((size_t)z*N + node)*HC + c;
  xl1[o] = clampf(al, -1e4f, 1e4f);
  xr1[o] = clampf(ar, -1e4f, 1e4f);
}
__global__ __launch_bounds__(256) void k_node1(const void* x, const void* Wl, const void* Wr,
    float* xl1, float* xr1, const int* flag, int b0){
  if (*flag) node1_body((const float*)x,(const float*)Wl,(const float*)Wr,xl1,xr1,b0);
  else       node1_body((const bf16*) x,(const bf16*) Wl,(const bf16*) Wr,xl1,xr1,b0);
}

// ---------------- conv1 edge scores -> exp directly + denominator ----------------
template<typename T>
__device__ __forceinline__ void score1_body(const int* ei, const T* ea, const T* We, const T* att,
    const float* xl1, const float* xr1, float* sc1, float* den1, int b0){
  int z = blockIdx.z, b = b0 + z;
  size_t e0 = (size_t)blockIdx.x * EPB1;
  int c = threadIdx.x; int cc = c & 15, h = c >> 4;
  __shared__ float eas[EPB1][ED];
  __shared__ int ss[EPB1], sd[EPB1];
  for (int i=threadIdx.x; i<EPB1*ED; i+=128)
    ((float*)eas)[i] = ldv(ea, ((size_t)b*E + e0)*ED + i);
  if (threadIdx.x < EPB1){
    ss[threadIdx.x] = ei[((size_t)b*2+0)*E + e0 + threadIdx.x];
    sd[threadIdx.x] = ei[((size_t)b*2+1)*E + e0 + threadIdx.x];
  }
  float w[ED];
  #pragma unroll
  for (int j=0;j<ED;j++) w[j] = ldv(We, (size_t)j*HC+c);
  float attc = ldv(att, (size_t)c);
  __syncthreads();
  const float* xlz = xl1 + (size_t)z*N*HC;
  const float* xrz = xr1 + (size_t)z*N*HC;
  #pragma unroll 4
  for (int el=0; el<EPB1; el++){
    int s = ss[el], d = sd[el];
    float ee = 0.f;
    #pragma unroll
    for (int j=0;j<ED;j++) ee += eas[el][j]*w[j];
    float g = xlz[(size_t)s*HC+c] + xrz[(size_t)d*HC+c] + ee;
    g = g>0.f ? g : 0.2f*g;
    float v = g*attc;
    v += __shfl_xor(v,1); v += __shfl_xor(v,2); v += __shfl_xor(v,4); v += __shfl_xor(v,8);
    if (cc==0){
      float ex = expf(clampf(v, -60.f, 60.f));
      sc1[((size_t)z*E + e0 + el)*8 + h] = ex;
      atomicAdd(&den1[((size_t)z*N + d)*8 + h], ex);
    }
  }
}
__global__ __launch_bounds__(128) void k_score1(const int* ei, const void* ea, const void* We, const void* att,
    const float* xl1, const float* xr1, float* sc1, float* den1, const int* flag, int b0){
  if (*flag) score1_body(ei,(const float*)ea,(const float*)We,(const float*)att,xl1,xr1,sc1,den1,b0);
  else       score1_body(ei,(const bf16*) ea,(const bf16*) We,(const bf16*) att,xl1,xr1,sc1,den1,b0);
}

// ---------------- conv1 aggregation (atomic into hx) ----------------
__global__ __launch_bounds__(128) void k_agg1(const int* __restrict__ ei, const float* __restrict__ sc1,
    const float* __restrict__ den1, const float* __restrict__ xl1, float* __restrict__ hx, int b0){
  int z = blockIdx.z, b = b0 + z;
  size_t e0 = (size_t)blockIdx.x * EPB1;
  int c = threadIdx.x; int h = c >> 4;
  __shared__ int ss[EPB1], sd[EPB1];
  __shared__ float sal[EPB1][8];
  if (threadIdx.x < EPB1){
    ss[threadIdx.x] = ei[((size_t)b*2+0)*E + e0 + threadIdx.x];
    sd[threadIdx.x] = ei[((size_t)b*2+1)*E + e0 + threadIdx.x];
  }
  __syncthreads();
  {
    int el = threadIdx.x >> 3, hh = threadIdx.x & 7;
    int d = sd[el];
    float ex = sc1[((size_t)z*E + e0 + el)*8 + hh];
    float dn = den1[((size_t)z*N + d)*8 + hh];
    sal[el][hh] = ex/(dn + 1e-16f);
  }
  __syncthreads();
  const float* xlz = xl1 + (size_t)z*N*HC;
  float* hxz = hx + (size_t)z*N*HC;
  #pragma unroll 4
  for (int el=0; el<EPB1; el++){
    int s = ss[el], d = sd[el];
    float v = xlz[(size_t)s*HC + c] * sal[el][h];
    atomicAdd(&hxz[(size_t)d*HC + c], v);
  }
}

// ---------------- bias + ELU in place ----------------
template<typename T>
__device__ __forceinline__ void elu_body(float* hx, const T* b1, int b0){
  int z = blockIdx.z;
  size_t t = (size_t)blockIdx.x*256 + threadIdx.x;
  if (t >= (size_t)N*HC) return;
  int c = t & 127;
  float h = hx[(size_t)z*N*HC + t] + ldv(b1, (size_t)c);
  hx[(size_t)z*N*HC + t] = h>0.f ? h : expm1f(h);
}
__global__ __launch_bounds__(256) void k_elu(float* hx, const void* b1, const int* flag, int b0){
  if (*flag) elu_body(hx,(const float*)b1,b0);
  else       elu_body(hx,(const bf16*) b1,b0);
}

// ---------------- conv2/conv3 node transforms (4 matrices at once) ----------------
template<typename T>
__device__ __forceinline__ void node2_body(const float* hx, const float* xl1,
    const T* W2l, const T* W2r, const T* W3l, const T* W3r,
    float* xl2, float* xr2, float* xl3, float* xr3, int b0){
  int z = blockIdx.z;
  int r = threadIdx.x >> 6;
  int lane = threadIdx.x & 63;
  int m = lane >> 4, c = lane & 15;
  int node = blockIdx.x*4 + r;
  __shared__ float hv[4][HC], sv[4][HC];
  for (int i=threadIdx.x; i<4*HC; i+=256){
    int rr = i >> 7, k = i & 127;
    size_t o = ((size_t)z*N + blockIdx.x*4 + rr)*HC + k;
    float hh = hx[o];
    hv[rr][k] = hh;
    sv[rr][k] = hh + xl1[o];           // hs = hx + skip(=xl1)
  }
  __syncthreads();
  const T* W = (m==0)? W2l : (m==1)? W2r : (m==2)? W3l : W3r;
  const float* vrow = (m<2)? hv[r] : sv[r];
  float acc = 0.f;
  #pragma unroll 8
  for (int k=0;k<HC;k++) acc += vrow[k]*ldv(W, (size_t)k*CH+c);
  float* outp = (m==0)? xl2 : (m==1)? xr2 : (m==2)? xl3 : xr3;
  outp[((size_t)z*N + node)*CH + c] = clampf(acc, -1e4f, 1e4f);
}
__global__ __launch_bounds__(256) void k_node2(const float* hx, const float* xl1,
    const void* W2l, const void* W2r, const void* W3l, const void* W3r,
    float* xl2, float* xr2, float* xl3, float* xr3, const int* flag, int b0){
  if (*flag) node2_body(hx,xl1,(const float*)W2l,(const float*)W2r,(const float*)W3l,(const float*)W3r,xl2,xr2,xl3,xr3,b0);
  else       node2_body(hx,xl1,(const bf16*) W2l,(const bf16*) W2r,(const bf16*) W3l,(const bf16*) W3r,xl2,xr2,xl3,xr3,b0);
}

// ---------------- conv2/conv3 edge scores -> exp directly + denominators ----------------
template<typename T>
__device__ __forceinline__ void score23_body(const int* ei, const T* ea,
    const T* We2, const T* We3, const T* att2, const T* att3,
    const float* xl2, const float* xr2, const float* xl3, const float* xr3,
    float* sc23, float* den2, int b0){
  int z = blockIdx.z, b = b0 + z;
  size_t e0 = (size_t)blockIdx.x * EPB2;
  int el = threadIdx.x >> 4, c = threadIdx.x & 15;
  size_t e = e0 + el;
  __shared__ float eas[EPB2][ED];
  __shared__ int ss[EPB2], sd[EPB2];
  ((float*)eas)[threadIdx.x] = ldv(ea, ((size_t)b*E + e0)*ED + threadIdx.x);
  if (threadIdx.x < EPB2){
    ss[threadIdx.x] = ei[((size_t)b*2+0)*E + e0 + threadIdx.x];
    sd[threadIdx.x] = ei[((size_t)b*2+1)*E + e0 + threadIdx.x];
  }
  __syncthreads();
  int s = ss[el], d = sd[el];
  float ee2=0.f, ee3=0.f;
  #pragma unroll
  for (int j=0;j<ED;j++){ float a = eas[el][j]; ee2 += a*ldv(We2,(size_t)j*CH+c); ee3 += a*ldv(We3,(size_t)j*CH+c); }
  size_t so = ((size_t)z*N + s)*CH + c, dof = ((size_t)z*N + d)*CH + c;
  float g2 = xl2[so] + xr2[dof] + ee2; g2 = g2>0.f? g2 : 0.2f*g2; float v2 = g2*ldv(att2,(size_t)c);
  float g3 = xl3[so] + xr3[dof] + ee3; g3 = g3>0.f? g3 : 0.2f*g3; float v3 = g3*ldv(att3,(size_t)c);
  v2 += __shfl_xor(v2,1); v2 += __shfl_xor(v2,2); v2 += __shfl_xor(v2,4); v2 += __shfl_xor(v2,8);
  v3 += __shfl_xor(v3,1); v3 += __shfl_xor(v3,2); v3 += __shfl_xor(v3,4); v3 += __shfl_xor(v3,8);
  if (c==0){
    float ex2 = expf(clampf(v2, -60.f, 60.f));
    float ex3 = expf(clampf(v3, -60.f, 60.f));
    sc23[((size_t)z*E + e)*2 + 0] = ex2;
    sc23[((size_t)z*E + e)*2 + 1] = ex3;
    atomicAdd(&den2[((size_t)z*N + d)*2 + 0], ex2);
    atomicAdd(&den2[((size_t)z*N + d)*2 + 1], ex3);
  }
}
__global__ __launch_bounds__(256) void k_score23(const int* ei, const void* ea,
    const void* We2, const void* We3, const void* att2, const void* att3,
    const float* xl2, const float* xr2, const float* xl3, const float* xr3,
    float* sc23, float* den2, const int* flag, int b0){
  if (*flag) score23_body(ei,(const float*)ea,(const float*)We2,(const float*)We3,(const float*)att2,(const float*)att3,xl2,xr2,xl3,xr3,sc23,den2,b0);
  else       score23_body(ei,(const bf16*) ea,(const bf16*) We2,(const bf16*) We3,(const bf16*) att2,(const bf16*) att3,xl2,xr2,xl3,xr3,sc23,den2,b0);
}

// ---------------- conv2/3 aggregation ----------------
__global__ __launch_bounds__(256) void k_agg23(const int* __restrict__ ei, const float* __restrict__ sc23,
    const float* __restrict__ den2, const float* __restrict__ xl2, const float* __restrict__ xl3,
    float* __restrict__ acc12, int b0){
  int z = blockIdx.z, b = b0 + z;
  size_t e0 = (size_t)blockIdx.x*8;
  int el = threadIdx.x >> 5, q = (threadIdx.x >> 4) & 1, c = threadIdx.x & 15;
  size_t e = e0 + el;
  int s = ei[((size_t)b*2+0)*E + e];
  int d = ei[((size_t)b*2+1)*E + e];
  float ex = sc23[((size_t)z*E + e)*2 + q];
  float dn = den2[((size_t)z*N + d)*2 + q];
  float alpha = ex/(dn + 1e-16f);
  const float* xp = q ? xl3 : xl2;
  float v = xp[((size_t)z*N + s)*CH + c]*alpha;
  atomicAdd(&acc12[((size_t)z*N + d)*32 + q*16 + c], v);
}

// ---------------- bias + linear + add + LayerNorm + store ----------------
template<typename T>
__device__ __forceinline__ void final_body(const float* acc12,
    const T* b2, const T* b3, const T* linW, const T* linb,
    const T* lng, const T* lnb, T* out, int b0){
  int z = blockIdx.z, b = b0 + z;
  int nl = threadIdx.x >> 4, c = threadIdx.x & 15;
  int node = blockIdx.x*16 + nl;
  float x1  = acc12[((size_t)z*N + node)*32 + c]      + ldv(b2,(size_t)c);
  float x2r = acc12[((size_t)z*N + node)*32 + 16 + c] + ldv(b3,(size_t)c);
  float x2 = 0.f;
  #pragma unroll
  for (int j=0;j<16;j++){
    float xj = __shfl(x2r, j, 16);
    x2 += xj * ldv(linW, (size_t)c*16 + j);  // x2 @ lin_W.T
  }
  x2 += ldv(linb,(size_t)c);
  float y = clampf(x1, -1e6f, 1e6f) + clampf(x2, -1e6f, 1e6f);
  float ssum = y;
  ssum += __shfl_xor(ssum,1); ssum += __shfl_xor(ssum,2); ssum += __shfl_xor(ssum,4); ssum += __shfl_xor(ssum,8);
  float mu = ssum*(1.f/16.f);
  float dv = y - mu; float vs = dv*dv;
  vs += __shfl_xor(vs,1); vs += __shfl_xor(vs,2); vs += __shfl_xor(vs,4); vs += __shfl_xor(vs,8);
  float var = vs*(1.f/16.f);
  float o = dv*rsqrtf(var + 1e-5f)*ldv(lng,(size_t)c) + ldv(lnb,(size_t)c);
  stv(out, ((size_t)b*N + node)*16 + c, o);
}
__global__ __launch_bounds__(256) void k_final(const float* acc12,
    const void* b2, const void* b3, const void* linW, const void* linb,
    const void* lng, const void* lnb, void* out, const int* flag, int b0){
  if (*flag) final_body(acc12,(const float*)b2,(const float*)b3,(const float*)linW,(const float*)linb,(const float*)lng,(const float*)lnb,(float*)out,b0);
  else       final_body(acc12,(const bf16*) b2,(const bf16*) b3,(const bf16*) linW,(const bf16*) linb,(const bf16*) lng,(const bf16*) lnb,(bf16*) out,b0);
}

// ---------------- workspace layout ----------------
struct WSP {
  int* flag;
  float *xl1,*xr1,*hx,*sc1,*den1;
  float *xl2,*xr2,*xl3,*xr3,*sc23,*den2,*acc12;
  size_t total;
};
static WSP mkws(char* base, int nb){
  WSP w; size_t off = 0;
  auto A = [&](size_t bytes)->char*{ char* p = base ? base + off : (char*)0; off = (off + bytes + 255) & ~(size_t)255; return p; };
  w.flag = (int*)  A(256);
  w.xl1  = (float*)A((size_t)nb*N*HC*4);
  w.xr1  = (float*)A((size_t)nb*N*HC*4);
  w.hx   = (float*)A((size_t)nb*N*HC*4);
  w.sc1  = (float*)A((size_t)nb*E*8*4);
  w.den1 = (float*)A((size_t)nb*N*8*4);
  w.xl2  = (float*)A((size_t)nb*N*CH*4);
  w.xr2  = (float*)A((size_t)nb*N*CH*4);
  w.xl3  = (float*)A((size_t)nb*N*CH*4);
  w.xr3  = (float*)A((size_t)nb*N*CH*4);
  w.sc23 = (float*)A((size_t)nb*E*2*4);
  w.den2 = (float*)A((size_t)nb*N*2*4);
  w.acc12= (float*)A((size_t)nb*N*32*4);
  w.total = off;
  return w;
}

extern "C" void kernel_launch(void* const* d_in, const int* in_sizes, int n_in,
                              void* d_out, int out_size, void* d_ws, size_t ws_size,
                              hipStream_t stream){
  const void* x    = d_in[0];
  const void* ea   = d_in[1];
  const int*  ei   = (const int*)d_in[2];
  const void* c1Wl = d_in[3], *c1Wr = d_in[4], *c1We = d_in[5];
  const void* c1att= d_in[6], *c1b  = d_in[7];
  const void* c2Wl = d_in[8], *c2Wr = d_in[9], *c2We = d_in[10];
  const void* c2att= d_in[11],*c2b  = d_in[12];
  const void* sWl  = d_in[13],*sWr  = d_in[14],*sWe  = d_in[15];
  const void* satt = d_in[16],*sb   = d_in[17];
  const void* linW = d_in[18],*linb = d_in[19];
  const void* lng  = d_in[20],*lnb  = d_in[21];

  auto run = [&](int b0, int nb){
    WSP w = mkws((char*)d_ws, nb);
    hipMemsetAsync(w.hx,   0, (size_t)nb*N*HC*4, stream);
    hipMemsetAsync(w.den1, 0, (size_t)nb*N*8*4,  stream);
    hipMemsetAsync(w.den2, 0, (size_t)nb*N*2*4,  stream);
    hipMemsetAsync(w.acc12,0, (size_t)nb*N*32*4, stream);
    k_node1  <<<dim3(N/2,1,nb),    256,0,stream>>>(x,c1Wl,c1Wr,w.xl1,w.xr1,w.flag,b0);
    k_score1 <<<dim3(E/EPB1,1,nb), 128,0,stream>>>(ei,ea,c1We,c1att,w.xl1,w.xr1,w.sc1,w.den1,w.flag,b0);
    k_agg1   <<<dim3(E/EPB1,1,nb), 128,0,stream>>>(ei,w.sc1,w.den1,w.xl1,w.hx,b0);
    k_elu    <<<dim3(N*HC/256,1,nb),256,0,stream>>>(w.hx,c1b,w.flag,b0);
    k_node2  <<<dim3(N/4,1,nb),    256,0,stream>>>(w.hx,w.xl1,c2Wl,c2Wr,sWl,sWr,w.xl2,w.xr2,w.xl3,w.xr3,w.flag,b0);
    k_score23<<<dim3(E/EPB2,1,nb), 256,0,stream>>>(ei,ea,c2We,sWe,c2att,satt,w.xl2,w.xr2,w.xl3,w.xr3,w.sc23,w.den2,w.flag,b0);
    k_agg23  <<<dim3(E/8,1,nb),    256,0,stream>>>(ei,w.sc23,w.den2,w.xl2,w.xl3,w.acc12,b0);
    k_final  <<<dim3(N/16,1,nb),   256,0,stream>>>(w.acc12,c2b,sb,linW,linb,lng,lnb,d_out,w.flag,b0);
  };

  // detect input dtype once per call (flag lives at ws offset 0 for any nb)
  {
    WSP w0 = mkws((char*)d_ws, 1);
    k_detect<<<1,256,0,stream>>>((const unsigned short*)x, w0.flag);
  }

  WSP probe = mkws((char*)0, NB_B);
  if (ws_size >= probe.total){
    run(0, NB_B);                          // single batched pass
  } else {
    for (int g=0; g<NB_B; ++g) run(g, 1);  // per-graph fallback
  }
}

// Round 4
// 2160.191 us; speedup vs baseline: 1.2423x; 1.2423x over previous
//
#include <hip/hip_runtime.h>
#include <hip/hip_bf16.h>

typedef __hip_bfloat16 bf16;

#define NB_B 4
#define N 20000
#define E 640000
#define F 64
#define HC 128   // conv1 heads*ch
#define ED 16
#define CH 16
#define NT 32    // nodes per tile in node-transform kernels

__device__ __forceinline__ float clampf(float v, float lo, float hi){ return fminf(fmaxf(v, lo), hi); }
// dtype-generic load/store
__device__ __forceinline__ float ldv(const float* p, size_t i){ return p[i]; }
__device__ __forceinline__ float ldv(const bf16*  p, size_t i){ return __bfloat162float(p[i]); }
__device__ __forceinline__ void  stv(float* p, size_t i, float v){ p[i] = v; }
__device__ __forceinline__ void  stv(bf16*  p, size_t i, float v){ p[i] = __float2bfloat16(v); }

// ---------------- dtype detector: f32 inputs (flag=1) vs bf16 (flag=0) ----------------
__global__ __launch_bounds__(256) void k_detect(const unsigned short* __restrict__ xu, int* __restrict__ flag){
  __shared__ int cnt[256];
  int tid = threadIdx.x;
  unsigned short lo = xu[2*tid];
  bf16 h = *(const bf16*)&lo;
  float v = fabsf(__bfloat162float(h));
  cnt[tid] = (v > 1e4f || (v != 0.f && v < 1e-4f)) ? 1 : 0;
  __syncthreads();
  for (int s=128; s>0; s>>=1){ if (tid<s) cnt[tid]+=cnt[tid+s]; __syncthreads(); }
  if (tid==0) *flag = (cnt[0] > 64) ? 1 : 0;
}

// ---------------- CSR build: histogram -> scan -> scatter ----------------
__global__ __launch_bounds__(256) void k_hist(const int* __restrict__ ei, int* __restrict__ cnt, int b0){
  int z = blockIdx.z, b = b0 + z;
  int e = blockIdx.x*256 + threadIdx.x;
  int d = ei[((size_t)b*2+1)*E + e];
  atomicAdd(&cnt[z*N + d], 1);
}

__global__ __launch_bounds__(256) void k_scan(const int* __restrict__ cnt, int* __restrict__ rowptr,
                                              int* __restrict__ cursor){
  int z = blockIdx.z, tid = threadIdx.x;
  const int* c = cnt + (size_t)z*N;
  int* rp = rowptr + (size_t)z*(N+1);
  int* cu = cursor + (size_t)z*N;
  __shared__ int buf[256];
  __shared__ int carry;
  if (tid==0) carry = 0;
  __syncthreads();
  for (int base=0; base<N; base+=256){
    int idx = base + tid;
    int v = (idx < N) ? c[idx] : 0;
    buf[tid] = v; __syncthreads();
    for (int off=1; off<256; off<<=1){
      int t = (tid >= off) ? buf[tid-off] : 0;
      __syncthreads();
      buf[tid] += t;
      __syncthreads();
    }
    int incl = buf[tid];
    int chunk_total = buf[255];
    int out = carry + incl - v;
    if (idx < N){ rp[idx] = out; cu[idx] = out; }
    __syncthreads();
    if (tid==0) carry += chunk_total;
    __syncthreads();
  }
  if (tid==0) rp[N] = carry;
}

__global__ __launch_bounds__(256) void k_scatter(const int* __restrict__ ei, int* __restrict__ cursor,
                                                 int2* __restrict__ csr, int b0){
  int z = blockIdx.z, b = b0 + z;
  int e = blockIdx.x*256 + threadIdx.x;
  int s = ei[((size_t)b*2+0)*E + e];
  int d = ei[((size_t)b*2+1)*E + e];
  int pos = atomicAdd(&cursor[z*N + d], 1);
  csr[(size_t)z*E + pos] = make_int2(s, e);
}

// ---------------- conv1 node transform: 32-node tile, weights amortized ----------------
template<typename T>
__device__ __forceinline__ void node1_body(const T* x, const T* Wl, const T* Wr,
                                           float* xl1, float* xr1, int b0){
  int z = blockIdx.z, b = b0 + z;
  int node0 = blockIdx.x*NT;
  __shared__ float xs[NT][F+1];
  for (int i=threadIdx.x; i<NT*F; i+=256){
    int n = i>>6, k = i&63;
    xs[n][k] = ldv(x, ((size_t)b*N + node0 + n)*F + k);
  }
  __syncthreads();
  int mat = threadIdx.x >> 7, c = threadIdx.x & 127;
  const T* W = mat ? Wr : Wl;
  float acc[NT];
  #pragma unroll
  for (int n=0;n<NT;n++) acc[n]=0.f;
  #pragma unroll 4
  for (int k=0;k<F;k++){
    float wv = ldv(W, (size_t)k*HC + c);
    #pragma unroll
    for (int n=0;n<NT;n++) acc[n] += xs[n][k]*wv;
  }
  float* outp = mat ? xr1 : xl1;
  #pragma unroll
  for (int n=0;n<NT;n++)
    outp[((size_t)z*N + node0 + n)*HC + c] = clampf(acc[n], -1e4f, 1e4f);
}
__global__ __launch_bounds__(256) void k_node1(const void* x, const void* Wl, const void* Wr,
    float* xl1, float* xr1, const int* flag, int b0){
  if (*flag) node1_body((const float*)x,(const float*)Wl,(const float*)Wr,xl1,xr1,b0);
  else       node1_body((const bf16*) x,(const bf16*) Wl,(const bf16*) Wr,xl1,xr1,b0);
}

// ---------------- conv1 fused gather: score + softmax + aggregate + bias + ELU ----------------
template<typename T>
__device__ __forceinline__ void gather1_body(const int* rowptr, const int2* csr,
    const T* ea, const T* We, const T* att, const T* b1,
    const float* xl1, const float* xr1, float* hx, int b0){
  int z = blockIdx.z, b = b0 + z;
  int node = blockIdx.x;
  int c = threadIdx.x, cc = c & 15;
  int rs = rowptr[(size_t)z*(N+1) + node];
  int re = rowptr[(size_t)z*(N+1) + node + 1];
  float xr1c = xr1[((size_t)z*N + node)*HC + c];
  float w[ED];
  #pragma unroll
  for (int j=0;j<ED;j++) w[j] = ldv(We, (size_t)j*HC + c);
  float attc = ldv(att, (size_t)c);
  float acc = 0.f, den = 0.f;
  __shared__ int2 se[64];
  for (int base = rs; base < re; base += 64){
    int m = re - base; if (m > 64) m = 64;
    __syncthreads();
    if (threadIdx.x < m) se[threadIdx.x] = csr[(size_t)z*E + base + threadIdx.x];
    __syncthreads();
    for (int i=0;i<m;i++){
      int s = se[i].x, e = se[i].y;
      float eav = ldv(ea, ((size_t)b*E + e)*ED + cc);
      float ee = 0.f;
      #pragma unroll
      for (int j=0;j<ED;j++) ee += __shfl(eav, j, 16) * w[j];
      float xlv = xl1[((size_t)z*N + s)*HC + c];
      float g = xlv + xr1c + ee;
      g = g>0.f ? g : 0.2f*g;
      float v = g*attc;
      v += __shfl_xor(v,1); v += __shfl_xor(v,2); v += __shfl_xor(v,4); v += __shfl_xor(v,8);
      float ex = __expf(clampf(v, -60.f, 60.f));
      den += ex;
      acc += ex*xlv;
    }
  }
  float hval = acc/(den + 1e-16f) + ldv(b1, (size_t)c);
  hx[((size_t)z*N + node)*HC + c] = hval>0.f ? hval : expm1f(hval);
}
__global__ __launch_bounds__(128) void k_gather1(const int* rowptr, const int2* csr,
    const void* ea, const void* We, const void* att, const void* b1,
    const float* xl1, const float* xr1, float* hx, const int* flag, int b0){
  if (*flag) gather1_body(rowptr,csr,(const float*)ea,(const float*)We,(const float*)att,(const float*)b1,xl1,xr1,hx,b0);
  else       gather1_body(rowptr,csr,(const bf16*) ea,(const bf16*) We,(const bf16*) att,(const bf16*) b1,xl1,xr1,hx,b0);
}

// ---------------- conv2/conv3 node transforms: 32-node tile ----------------
template<typename T>
__device__ __forceinline__ void node2_body(const float* hx, const float* xl1,
    const T* W2l, const T* W2r, const T* W3l, const T* W3r,
    float* xl2, float* xr2, float* xl3, float* xr3, int b0){
  int z = blockIdx.z;
  int node0 = blockIdx.x*NT;
  __shared__ float hv[NT][HC+1], sv[NT][HC+1];
  for (int i=threadIdx.x; i<NT*HC; i+=256){
    int n = i>>7, k = i&127;
    size_t o = ((size_t)z*N + node0 + n)*HC + k;
    float h = hx[o];
    hv[n][k] = h;
    sv[n][k] = h + xl1[o];            // hs = hx + skip(=xl1)
  }
  __syncthreads();
  int o = threadIdx.x & 63;
  int mat = o >> 4, c = o & 15;
  int g = threadIdx.x >> 6;           // node sub-tile 0..3 (8 nodes each)
  const T* W = (mat==0)? W2l : (mat==1)? W2r : (mat==2)? W3l : W3r;
  float (*src)[HC+1] = (mat<2)? hv : sv;
  float acc[8];
  #pragma unroll
  for (int j=0;j<8;j++) acc[j]=0.f;
  #pragma unroll 4
  for (int k=0;k<HC;k++){
    float wv = ldv(W, (size_t)k*CH + c);
    #pragma unroll
    for (int j=0;j<8;j++) acc[j] += src[g*8+j][k]*wv;
  }
  float* outp = (mat==0)? xl2 : (mat==1)? xr2 : (mat==2)? xl3 : xr3;
  #pragma unroll
  for (int j=0;j<8;j++)
    outp[((size_t)z*N + node0 + g*8 + j)*CH + c] = clampf(acc[j], -1e4f, 1e4f);
}
__global__ __launch_bounds__(256) void k_node2(const float* hx, const float* xl1,
    const void* W2l, const void* W2r, const void* W3l, const void* W3r,
    float* xl2, float* xr2, float* xl3, float* xr3, const int* flag, int b0){
  if (*flag) node2_body(hx,xl1,(const float*)W2l,(const float*)W2r,(const float*)W3l,(const float*)W3r,xl2,xr2,xl3,xr3,b0);
  else       node2_body(hx,xl1,(const bf16*) W2l,(const bf16*) W2r,(const bf16*) W3l,(const bf16*) W3r,xl2,xr2,xl3,xr3,b0);
}

// ---------------- conv2+conv3 fused gather + linear + LayerNorm + store ----------------
template<typename T>
__device__ __forceinline__ void gather23_body(const int* rowptr, const int2* csr,
    const T* ea, const T* We2, const T* We3, const T* att2, const T* att3,
    const T* b2, const T* b3, const T* linW, const T* linb, const T* lng, const T* lnb,
    const float* xl2, const float* xr2, const float* xl3, const float* xr3,
    T* out, int b0){
  int z = blockIdx.z, b = b0 + z;
  int slot = threadIdx.x >> 5;
  int node = blockIdx.x*8 + slot;
  int t32 = threadIdx.x & 31;
  int q = t32 >> 4, c = t32 & 15;
  int rs = rowptr[(size_t)z*(N+1) + node];
  int re = rowptr[(size_t)z*(N+1) + node + 1];
  const float* xlq = q ? xl3 : xl2;
  float xrv = (q ? xr3 : xr2)[((size_t)z*N + node)*CH + c];
  const T* Weq = q ? We3 : We2;
  float w[ED];
  #pragma unroll
  for (int j=0;j<ED;j++) w[j] = ldv(Weq, (size_t)j*CH + c);
  float attc = q ? ldv(att3,(size_t)c) : ldv(att2,(size_t)c);
  float acc = 0.f, den = 0.f;
  for (int i=rs; i<re; i++){
    int2 se = csr[(size_t)z*E + i];
    int s = se.x, e = se.y;
    float eav = ldv(ea, ((size_t)b*E + e)*ED + c);
    float ee = 0.f;
    #pragma unroll
    for (int j=0;j<ED;j++) ee += __shfl(eav, j, 16) * w[j];
    float xlv = xlq[((size_t)z*N + s)*CH + c];
    float g = xlv + xrv + ee;
    g = g>0.f ? g : 0.2f*g;
    float v = g*attc;
    v += __shfl_xor(v,1); v += __shfl_xor(v,2); v += __shfl_xor(v,4); v += __shfl_xor(v,8);
    float ex = __expf(clampf(v, -60.f, 60.f));
    den += ex;
    acc += ex*xlv;
  }
  float xq = acc/(den + 1e-16f) + (q ? ldv(b3,(size_t)c) : ldv(b2,(size_t)c));
  // linear layer on conv3 result (q==1 lanes); garbage on q==0 lanes (unused)
  float x2 = 0.f;
  #pragma unroll
  for (int j=0;j<16;j++) x2 += __shfl(xq, j, 16) * ldv(linW, (size_t)c*16 + j);
  x2 += ldv(linb,(size_t)c);
  float myv = q ? x2 : xq;
  float partner = __shfl(myv, t32 ^ 16, 32);
  float y = clampf(myv, -1e6f, 1e6f) + clampf(partner, -1e6f, 1e6f);
  float ssum = y;
  ssum += __shfl_xor(ssum,1); ssum += __shfl_xor(ssum,2); ssum += __shfl_xor(ssum,4); ssum += __shfl_xor(ssum,8);
  float mu = ssum*(1.f/16.f);
  float dv = y - mu; float vs = dv*dv;
  vs += __shfl_xor(vs,1); vs += __shfl_xor(vs,2); vs += __shfl_xor(vs,4); vs += __shfl_xor(vs,8);
  float var = vs*(1.f/16.f);
  float o = dv*rsqrtf(var + 1e-5f)*ldv(lng,(size_t)c) + ldv(lnb,(size_t)c);
  if (q==0) stv(out, ((size_t)b*N + node)*16 + c, o);
}
__global__ __launch_bounds__(256) void k_gather23(const int* rowptr, const int2* csr,
    const void* ea, const void* We2, const void* We3, const void* att2, const void* att3,
    const void* b2, const void* b3, const void* linW, const void* linb, const void* lng, const void* lnb,
    const float* xl2, const float* xr2, const float* xl3, const float* xr3,
    void* out, const int* flag, int b0){
  if (*flag) gather23_body(rowptr,csr,(const float*)ea,(const float*)We2,(const float*)We3,(const float*)att2,(const float*)att3,
                           (const float*)b2,(const float*)b3,(const float*)linW,(const float*)linb,(const float*)lng,(const float*)lnb,
                           xl2,xr2,xl3,xr3,(float*)out,b0);
  else       gather23_body(rowptr,csr,(const bf16*) ea,(const bf16*) We2,(const bf16*) We3,(const bf16*) att2,(const bf16*) att3,
                           (const bf16*) b2,(const bf16*) b3,(const bf16*) linW,(const bf16*) linb,(const bf16*) lng,(const bf16*) lnb,
                           xl2,xr2,xl3,xr3,(bf16*) out,b0);
}

// ---------------- workspace layout ----------------
struct WSP {
  int* flag;
  int *cnt, *cursor, *rowptr; int2* csr;
  float *xl1,*xr1,*hx,*xl2,*xr2,*xl3,*xr3;
  size_t total;
};
static WSP mkws(char* base, int nb){
  WSP w; size_t off = 0;
  auto A = [&](size_t bytes)->char*{ char* p = base ? base + off : (char*)0; off = (off + bytes + 255) & ~(size_t)255; return p; };
  w.flag   = (int*)  A(256);
  w.cnt    = (int*)  A((size_t)nb*N*4);
  w.cursor = (int*)  A((size_t)nb*N*4);
  w.rowptr = (int*)  A((size_t)nb*(N+1)*4);
  w.csr    = (int2*) A((size_t)nb*E*8);
  w.xl1    = (float*)A((size_t)nb*N*HC*4);
  w.xr1    = (float*)A((size_t)nb*N*HC*4);
  w.hx     = (float*)A((size_t)nb*N*HC*4);
  w.xl2    = (float*)A((size_t)nb*N*CH*4);
  w.xr2    = (float*)A((size_t)nb*N*CH*4);
  w.xl3    = (float*)A((size_t)nb*N*CH*4);
  w.xr3    = (float*)A((size_t)nb*N*CH*4);
  w.total = off;
  return w;
}

extern "C" void kernel_launch(void* const* d_in, const int* in_sizes, int n_in,
                              void* d_out, int out_size, void* d_ws, size_t ws_size,
                              hipStream_t stream){
  const void* x    = d_in[0];
  const void* ea   = d_in[1];
  const int*  ei   = (const int*)d_in[2];
  const void* c1Wl = d_in[3], *c1Wr = d_in[4], *c1We = d_in[5];
  const void* c1att= d_in[6], *c1b  = d_in[7];
  const void* c2Wl = d_in[8], *c2Wr = d_in[9], *c2We = d_in[10];
  const void* c2att= d_in[11],*c2b  = d_in[12];
  const void* sWl  = d_in[13],*sWr  = d_in[14],*sWe  = d_in[15];
  const void* satt = d_in[16],*sb   = d_in[17];
  const void* linW = d_in[18],*linb = d_in[19];
  const void* lng  = d_in[20],*lnb  = d_in[21];

  auto run = [&](int b0, int nb){
    WSP w = mkws((char*)d_ws, nb);
    hipMemsetAsync(w.cnt, 0, (size_t)nb*N*4, stream);
    // CSR build (shared by all three convs)
    k_hist   <<<dim3(E/256,1,nb), 256,0,stream>>>(ei, w.cnt, b0);
    k_scan   <<<dim3(1,1,nb),     256,0,stream>>>(w.cnt, w.rowptr, w.cursor);
    k_scatter<<<dim3(E/256,1,nb), 256,0,stream>>>(ei, w.cursor, w.csr, b0);
    // conv1
    k_node1  <<<dim3(N/NT,1,nb),  256,0,stream>>>(x, c1Wl, c1Wr, w.xl1, w.xr1, w.flag, b0);
    k_gather1<<<dim3(N,1,nb),     128,0,stream>>>(w.rowptr, w.csr, ea, c1We, c1att, c1b,
                                                  w.xl1, w.xr1, w.hx, w.flag, b0);
    // conv2 + skip-conv
    k_node2  <<<dim3(N/NT,1,nb),  256,0,stream>>>(w.hx, w.xl1, c2Wl, c2Wr, sWl, sWr,
                                                  w.xl2, w.xr2, w.xl3, w.xr3, w.flag, b0);
    k_gather23<<<dim3(N/8,1,nb),  256,0,stream>>>(w.rowptr, w.csr, ea, c2We, sWe, c2att, satt,
                                                  c2b, sb, linW, linb, lng, lnb,
                                                  w.xl2, w.xr2, w.xl3, w.xr3, d_out, w.flag, b0);
  };

  {
    WSP w0 = mkws((char*)d_ws, 1);
    k_detect<<<1,256,0,stream>>>((const unsigned short*)x, w0.flag);
  }

  WSP probe = mkws((char*)0, NB_B);
  if (ws_size >= probe.total){
    run(0, NB_B);                          // single batched pass
  } else {
    for (int g=0; g<NB_B; ++g) run(g, 1);  // per-graph fallback
  }
}

// Round 5
// 1572.270 us; speedup vs baseline: 1.7068x; 1.3739x over previous
//
#include <hip/hip_runtime.h>
#include <hip/hip_bf16.h>

typedef __hip_bfloat16 bf16;

#define NB_B 4
#define N 20000
#define E 640000
#define F 64
#define HC 128   // conv1 heads*ch
#define ED 16
#define CH 16
#define NT 32    // nodes per tile in node-transform kernels
#define TB1 64   // edge tile, gather1
#define TB2 16   // edge tile per slot, gather23

__device__ __forceinline__ float clampf(float v, float lo, float hi){ return fminf(fmaxf(v, lo), hi); }
__device__ __forceinline__ float ldv(const float* p, size_t i){ return p[i]; }
__device__ __forceinline__ float ldv(const bf16*  p, size_t i){ return __bfloat162float(p[i]); }
__device__ __forceinline__ void  stv(float* p, size_t i, float v){ p[i] = v; }
__device__ __forceinline__ void  stv(bf16*  p, size_t i, float v){ p[i] = __float2bfloat16(v); }
__device__ __forceinline__ unsigned packbf(float lo, float hi){
  bf16 a = __float2bfloat16(lo), b = __float2bfloat16(hi);
  return (unsigned)(*(unsigned short*)&a) | ((unsigned)(*(unsigned short*)&b) << 16);
}
__device__ __forceinline__ float unpl(unsigned u){ return __uint_as_float(u << 16); }
__device__ __forceinline__ float unph(unsigned u){ return __uint_as_float(u & 0xffff0000u); }

// ---------------- dtype detector: f32 inputs (flag=1) vs bf16 (flag=0) ----------------
__global__ __launch_bounds__(256) void k_detect(const unsigned short* __restrict__ xu, int* __restrict__ flag){
  __shared__ int cnt[256];
  int tid = threadIdx.x;
  unsigned short lo = xu[2*tid];
  bf16 h = *(const bf16*)&lo;
  float v = fabsf(__bfloat162float(h));
  cnt[tid] = (v > 1e4f || (v != 0.f && v < 1e-4f)) ? 1 : 0;
  __syncthreads();
  for (int s=128; s>0; s>>=1){ if (tid<s) cnt[tid]+=cnt[tid+s]; __syncthreads(); }
  if (tid==0) *flag = (cnt[0] > 64) ? 1 : 0;
}

// ---------------- CSR build: histogram -> scan -> scatter ----------------
__global__ __launch_bounds__(256) void k_hist(const int* __restrict__ ei, int* __restrict__ cnt, int b0){
  int z = blockIdx.z, b = b0 + z;
  int e = blockIdx.x*256 + threadIdx.x;
  int d = ei[((size_t)b*2+1)*E + e];
  atomicAdd(&cnt[z*N + d], 1);
}

__global__ __launch_bounds__(256) void k_scan(const int* __restrict__ cnt, int* __restrict__ rowptr,
                                              int* __restrict__ cursor){
  int z = blockIdx.z, tid = threadIdx.x;
  const int* c = cnt + (size_t)z*N;
  int* rp = rowptr + (size_t)z*(N+1);
  int* cu = cursor + (size_t)z*N;
  __shared__ int buf[256];
  __shared__ int carry;
  if (tid==0) carry = 0;
  __syncthreads();
  for (int base=0; base<N; base+=256){
    int idx = base + tid;
    int v = (idx < N) ? c[idx] : 0;
    buf[tid] = v; __syncthreads();
    for (int off=1; off<256; off<<=1){
      int t = (tid >= off) ? buf[tid-off] : 0;
      __syncthreads();
      buf[tid] += t;
      __syncthreads();
    }
    int incl = buf[tid];
    int chunk_total = buf[255];
    int out = carry + incl - v;
    if (idx < N){ rp[idx] = out; cu[idx] = out; }
    __syncthreads();
    if (tid==0) carry += chunk_total;
    __syncthreads();
  }
  if (tid==0) rp[N] = carry;
}

__global__ __launch_bounds__(256) void k_scatter(const int* __restrict__ ei, int* __restrict__ cursor,
                                                 int2* __restrict__ csr, int b0){
  int z = blockIdx.z, b = b0 + z;
  int e = blockIdx.x*256 + threadIdx.x;
  int s = ei[((size_t)b*2+0)*E + e];
  int d = ei[((size_t)b*2+1)*E + e];
  int pos = atomicAdd(&cursor[z*N + d], 1);
  csr[(size_t)z*E + pos] = make_int2(s, e);
}

// ---------------- conv1 node transform: 32-node tile ----------------
template<typename T>
__device__ __forceinline__ void node1_body(const T* x, const T* Wl, const T* Wr,
                                           float* xl1, float* xr1, int b0){
  int z = blockIdx.z, b = b0 + z;
  int node0 = blockIdx.x*NT;
  __shared__ float xs[NT][F+1];
  for (int i=threadIdx.x; i<NT*F; i+=256){
    int n = i>>6, k = i&63;
    xs[n][k] = ldv(x, ((size_t)b*N + node0 + n)*F + k);
  }
  __syncthreads();
  int mat = threadIdx.x >> 7, c = threadIdx.x & 127;
  const T* W = mat ? Wr : Wl;
  float acc[NT];
  #pragma unroll
  for (int n=0;n<NT;n++) acc[n]=0.f;
  #pragma unroll 4
  for (int k=0;k<F;k++){
    float wv = ldv(W, (size_t)k*HC + c);
    #pragma unroll
    for (int n=0;n<NT;n++) acc[n] += xs[n][k]*wv;
  }
  float* outp = mat ? xr1 : xl1;
  #pragma unroll
  for (int n=0;n<NT;n++)
    outp[((size_t)z*N + node0 + n)*HC + c] = clampf(acc[n], -1e4f, 1e4f);
}
__global__ __launch_bounds__(256) void k_node1(const void* x, const void* Wl, const void* Wr,
    float* xl1, float* xr1, const int* flag, int b0){
  if (*flag) node1_body((const float*)x,(const float*)Wl,(const float*)Wr,xl1,xr1,b0);
  else       node1_body((const bf16*) x,(const bf16*) Wl,(const bf16*) Wr,xl1,xr1,b0);
}

// ---------------- pack conv1 node features: (c, c+64) bf16 pairs ----------------
__global__ __launch_bounds__(256) void k_pack1(const float* __restrict__ xl1, const float* __restrict__ xr1,
    unsigned* __restrict__ xl1p, unsigned* __restrict__ xr1p){
  int z = blockIdx.z;
  size_t t = (size_t)blockIdx.x*256 + threadIdx.x;     // over N*64
  size_t n = t >> 6; int p = (int)(t & 63);
  size_t base = ((size_t)z*N + n)*HC;
  xl1p[((size_t)z*N + n)*64 + p] = packbf(xl1[base + p], xl1[base + p + 64]);
  xr1p[((size_t)z*N + n)*64 + p] = packbf(xr1[base + p], xr1[base + p + 64]);
}

// ---------------- conv1 fused gather: wave-per-node, channel-pair lanes ----------------
template<typename T>
__device__ __forceinline__ void gather1_body(const int* rowptr, const int2* csr,
    const T* ea, const T* We, const T* att, const T* b1,
    const unsigned* xl1p, const unsigned* xr1p, float* hx, int b0){
  int z = blockIdx.z, b = b0 + z;
  int wid = threadIdx.x >> 6, lane = threadIdx.x & 63;
  int node = blockIdx.x*4 + wid;
  __shared__ int2 sse[4][TB1];
  __shared__ float eas[4][TB1][16];
  int rs = rowptr[(size_t)z*(N+1) + node];
  int re = rowptr[(size_t)z*(N+1) + node + 1];
  unsigned xru = xr1p[((size_t)z*N + node)*64 + lane];
  float xrL = unpl(xru), xrH = unph(xru);
  float wL[ED], wH[ED];
  #pragma unroll
  for (int j=0;j<ED;j++){ wL[j] = ldv(We, (size_t)j*HC + lane); wH[j] = ldv(We, (size_t)j*HC + lane + 64); }
  float attL = ldv(att, (size_t)lane), attH = ldv(att, (size_t)lane + 64);
  float accL = 0.f, accH = 0.f, denL = 0.f, denH = 0.f;
  for (int base = rs; base < re; base += TB1){
    int m = re - base; if (m > TB1) m = TB1;
    if (lane < m) sse[wid][lane] = csr[(size_t)z*E + base + lane];
    for (int i=lane; i<m*ED; i+=64){
      int e = sse[wid][i>>4].y;
      eas[wid][i>>4][i&15] = ldv(ea, ((size_t)b*E + e)*ED + (i&15));
    }
    for (int i=0;i<m;i++){
      int s = sse[wid][i].x;
      unsigned xv = xl1p[((size_t)z*N + s)*64 + lane];
      float xlL = unpl(xv), xlH = unph(xv);
      float ev[16];
      const float4* er = (const float4*)eas[wid][i];
      *(float4*)&ev[0]  = er[0];
      *(float4*)&ev[4]  = er[1];
      *(float4*)&ev[8]  = er[2];
      *(float4*)&ev[12] = er[3];
      float eeL = 0.f, eeH = 0.f;
      #pragma unroll
      for (int j=0;j<ED;j++){ eeL += ev[j]*wL[j]; eeH += ev[j]*wH[j]; }
      float gL = xlL + xrL + eeL; gL = gL>0.f ? gL : 0.2f*gL;
      float gH = xlH + xrH + eeH; gH = gH>0.f ? gH : 0.2f*gH;
      float vL = gL*attL, vH = gH*attH;
      vL += __shfl_xor(vL,1); vL += __shfl_xor(vL,2); vL += __shfl_xor(vL,4); vL += __shfl_xor(vL,8);
      vH += __shfl_xor(vH,1); vH += __shfl_xor(vH,2); vH += __shfl_xor(vH,4); vH += __shfl_xor(vH,8);
      float exL = __expf(clampf(vL, -60.f, 60.f));
      float exH = __expf(clampf(vH, -60.f, 60.f));
      denL += exL; denH += exH;
      accL += exL*xlL; accH += exH*xlH;
    }
  }
  float hL = accL/(denL + 1e-16f) + ldv(b1, (size_t)lane);
  float hH = accH/(denH + 1e-16f) + ldv(b1, (size_t)lane + 64);
  hL = hL>0.f ? hL : expm1f(hL);
  hH = hH>0.f ? hH : expm1f(hH);
  hx[((size_t)z*N + node)*HC + lane]      = hL;
  hx[((size_t)z*N + node)*HC + lane + 64] = hH;
}
__global__ __launch_bounds__(256) void k_gather1(const int* rowptr, const int2* csr,
    const void* ea, const void* We, const void* att, const void* b1,
    const unsigned* xl1p, const unsigned* xr1p, float* hx, const int* flag, int b0){
  if (*flag) gather1_body(rowptr,csr,(const float*)ea,(const float*)We,(const float*)att,(const float*)b1,xl1p,xr1p,hx,b0);
  else       gather1_body(rowptr,csr,(const bf16*) ea,(const bf16*) We,(const bf16*) att,(const bf16*) b1,xl1p,xr1p,hx,b0);
}

// ---------------- conv2/conv3 node transforms: 32-node tile ----------------
template<typename T>
__device__ __forceinline__ void node2_body(const float* hx, const float* xl1,
    const T* W2l, const T* W2r, const T* W3l, const T* W3r,
    float* xl2, float* xr2, float* xl3, float* xr3, int b0){
  int z = blockIdx.z;
  int node0 = blockIdx.x*NT;
  __shared__ float hv[NT][HC+1], sv[NT][HC+1];
  for (int i=threadIdx.x; i<NT*HC; i+=256){
    int n = i>>7, k = i&127;
    size_t o = ((size_t)z*N + node0 + n)*HC + k;
    float h = hx[o];
    hv[n][k] = h;
    sv[n][k] = h + xl1[o];            // hs = hx + skip(=xl1)
  }
  __syncthreads();
  int o = threadIdx.x & 63;
  int mat = o >> 4, c = o & 15;
  int g = threadIdx.x >> 6;
  const T* W = (mat==0)? W2l : (mat==1)? W2r : (mat==2)? W3l : W3r;
  float (*src)[HC+1] = (mat<2)? hv : sv;
  float acc[8];
  #pragma unroll
  for (int j=0;j<8;j++) acc[j]=0.f;
  #pragma unroll 4
  for (int k=0;k<HC;k++){
    float wv = ldv(W, (size_t)k*CH + c);
    #pragma unroll
    for (int j=0;j<8;j++) acc[j] += src[g*8+j][k]*wv;
  }
  float* outp = (mat==0)? xl2 : (mat==1)? xr2 : (mat==2)? xl3 : xr3;
  #pragma unroll
  for (int j=0;j<8;j++)
    outp[((size_t)z*N + node0 + g*8 + j)*CH + c] = clampf(acc[j], -1e4f, 1e4f);
}
__global__ __launch_bounds__(256) void k_node2(const float* hx, const float* xl1,
    const void* W2l, const void* W2r, const void* W3l, const void* W3r,
    float* xl2, float* xr2, float* xl3, float* xr3, const int* flag, int b0){
  if (*flag) node2_body(hx,xl1,(const float*)W2l,(const float*)W2r,(const float*)W3l,(const float*)W3r,xl2,xr2,xl3,xr3,b0);
  else       node2_body(hx,xl1,(const bf16*) W2l,(const bf16*) W2r,(const bf16*) W3l,(const bf16*) W3r,xl2,xr2,xl3,xr3,b0);
}

// ---------------- pack conv2/3 node features: (xl2,xl3) and (xr2,xr3) bf16 pairs ----------------
__global__ __launch_bounds__(256) void k_pack2(const float* __restrict__ xl2, const float* __restrict__ xr2,
    const float* __restrict__ xl3, const float* __restrict__ xr3,
    unsigned* __restrict__ xl23p, unsigned* __restrict__ xr23p){
  int z = blockIdx.z;
  size_t t = (size_t)blockIdx.x*256 + threadIdx.x;     // over N*16
  size_t o = (size_t)z*N*CH + t;
  xl23p[o] = packbf(xl2[o], xl3[o]);
  xr23p[o] = packbf(xr2[o], xr3[o]);
}

// ---------------- conv2+conv3 fused gather + linear + LayerNorm + store ----------------
template<typename T>
__device__ __forceinline__ void gather23_body(const int* rowptr, const int2* csr,
    const T* ea, const T* We2, const T* We3, const T* att2, const T* att3,
    const T* b2, const T* b3, const T* linW, const T* linb, const T* lng, const T* lnb,
    const unsigned* xl23p, const unsigned* xr23p,
    T* out, int b0){
  int z = blockIdx.z, b = b0 + z;
  int slot = threadIdx.x >> 5;
  int node = blockIdx.x*8 + slot;
  int t32 = threadIdx.x & 31;
  int q = t32 >> 4, c = t32 & 15;
  __shared__ int2 sse[8][TB2];
  __shared__ float eas[8][TB2][16];
  int rs = rowptr[(size_t)z*(N+1) + node];
  int re = rowptr[(size_t)z*(N+1) + node + 1];
  unsigned xru = xr23p[((size_t)z*N + node)*CH + c];
  float xrv = q ? unph(xru) : unpl(xru);
  const T* Weq = q ? We3 : We2;
  float w[ED];
  #pragma unroll
  for (int j=0;j<ED;j++) w[j] = ldv(Weq, (size_t)j*CH + c);
  float attc = q ? ldv(att3,(size_t)c) : ldv(att2,(size_t)c);
  float acc = 0.f, den = 0.f;
  for (int base = rs; base < re; base += TB2){
    int m = re - base; if (m > TB2) m = TB2;
    if (t32 < m) sse[slot][t32] = csr[(size_t)z*E + base + t32];
    for (int i=t32; i<m*ED; i+=32){
      int e = sse[slot][i>>4].y;
      eas[slot][i>>4][i&15] = ldv(ea, ((size_t)b*E + e)*ED + (i&15));
    }
    for (int i=0;i<m;i++){
      int s = sse[slot][i].x;
      unsigned xv = xl23p[((size_t)z*N + s)*CH + c];
      float xlv = q ? unph(xv) : unpl(xv);
      float ev[16];
      const float4* er = (const float4*)eas[slot][i];
      *(float4*)&ev[0]  = er[0];
      *(float4*)&ev[4]  = er[1];
      *(float4*)&ev[8]  = er[2];
      *(float4*)&ev[12] = er[3];
      float ee = 0.f;
      #pragma unroll
      for (int j=0;j<ED;j++) ee += ev[j]*w[j];
      float g = xlv + xrv + ee;
      g = g>0.f ? g : 0.2f*g;
      float v = g*attc;
      v += __shfl_xor(v,1); v += __shfl_xor(v,2); v += __shfl_xor(v,4); v += __shfl_xor(v,8);
      float ex = __expf(clampf(v, -60.f, 60.f));
      den += ex;
      acc += ex*xlv;
    }
  }
  float xq = acc/(den + 1e-16f) + (q ? ldv(b3,(size_t)c) : ldv(b2,(size_t)c));
  float x2 = 0.f;
  #pragma unroll
  for (int j=0;j<16;j++) x2 += __shfl(xq, j, 16) * ldv(linW, (size_t)c*16 + j);
  x2 += ldv(linb,(size_t)c);
  float myv = q ? x2 : xq;
  float partner = __shfl(myv, t32 ^ 16, 32);
  float y = clampf(myv, -1e6f, 1e6f) + clampf(partner, -1e6f, 1e6f);
  float ssum = y;
  ssum += __shfl_xor(ssum,1); ssum += __shfl_xor(ssum,2); ssum += __shfl_xor(ssum,4); ssum += __shfl_xor(ssum,8);
  float mu = ssum*(1.f/16.f);
  float dv = y - mu; float vs = dv*dv;
  vs += __shfl_xor(vs,1); vs += __shfl_xor(vs,2); vs += __shfl_xor(vs,4); vs += __shfl_xor(vs,8);
  float var = vs*(1.f/16.f);
  float o = dv*rsqrtf(var + 1e-5f)*ldv(lng,(size_t)c) + ldv(lnb,(size_t)c);
  if (q==0) stv(out, ((size_t)(b0+z)*N + node)*16 + c, o);
}
__global__ __launch_bounds__(256) void k_gather23(const int* rowptr, const int2* csr,
    const void* ea, const void* We2, const void* We3, const void* att2, const void* att3,
    const void* b2, const void* b3, const void* linW, const void* linb, const void* lng, const void* lnb,
    const unsigned* xl23p, const unsigned* xr23p,
    void* out, const int* flag, int b0){
  if (*flag) gather23_body(rowptr,csr,(const float*)ea,(const float*)We2,(const float*)We3,(const float*)att2,(const float*)att3,
                           (const float*)b2,(const float*)b3,(const float*)linW,(const float*)linb,(const float*)lng,(const float*)lnb,
                           xl23p,xr23p,(float*)out,b0);
  else       gather23_body(rowptr,csr,(const bf16*) ea,(const bf16*) We2,(const bf16*) We3,(const bf16*) att2,(const bf16*) att3,
                           (const bf16*) b2,(const bf16*) b3,(const bf16*) linW,(const bf16*) linb,(const bf16*) lng,(const bf16*) lnb,
                           xl23p,xr23p,(bf16*) out,b0);
}

// ---------------- workspace layout ----------------
struct WSP {
  int* flag;
  int *cnt, *cursor, *rowptr; int2* csr;
  float *xl1,*xr1,*hx,*xl2,*xr2,*xl3,*xr3;
  unsigned *xl1p,*xr1p,*xl23p,*xr23p;
  size_t total;
};
static WSP mkws(char* base, int nb){
  WSP w; size_t off = 0;
  auto A = [&](size_t bytes)->char*{ char* p = base ? base + off : (char*)0; off = (off + bytes + 255) & ~(size_t)255; return p; };
  w.flag   = (int*)     A(256);
  w.cnt    = (int*)     A((size_t)nb*N*4);
  w.cursor = (int*)     A((size_t)nb*N*4);
  w.rowptr = (int*)     A((size_t)nb*(N+1)*4);
  w.csr    = (int2*)    A((size_t)nb*E*8);
  w.xl1    = (float*)   A((size_t)nb*N*HC*4);
  w.xr1    = (float*)   A((size_t)nb*N*HC*4);
  w.hx     = (float*)   A((size_t)nb*N*HC*4);
  w.xl2    = (float*)   A((size_t)nb*N*CH*4);
  w.xr2    = (float*)   A((size_t)nb*N*CH*4);
  w.xl3    = (float*)   A((size_t)nb*N*CH*4);
  w.xr3    = (float*)   A((size_t)nb*N*CH*4);
  w.xl1p   = (unsigned*)A((size_t)nb*N*64*4);
  w.xr1p   = (unsigned*)A((size_t)nb*N*64*4);
  w.xl23p  = (unsigned*)A((size_t)nb*N*CH*4);
  w.xr23p  = (unsigned*)A((size_t)nb*N*CH*4);
  w.total = off;
  return w;
}

extern "C" void kernel_launch(void* const* d_in, const int* in_sizes, int n_in,
                              void* d_out, int out_size, void* d_ws, size_t ws_size,
                              hipStream_t stream){
  const void* x    = d_in[0];
  const void* ea   = d_in[1];
  const int*  ei   = (const int*)d_in[2];
  const void* c1Wl = d_in[3], *c1Wr = d_in[4], *c1We = d_in[5];
  const void* c1att= d_in[6], *c1b  = d_in[7];
  const void* c2Wl = d_in[8], *c2Wr = d_in[9], *c2We = d_in[10];
  const void* c2att= d_in[11],*c2b  = d_in[12];
  const void* sWl  = d_in[13],*sWr  = d_in[14],*sWe  = d_in[15];
  const void* satt = d_in[16],*sb   = d_in[17];
  const void* linW = d_in[18],*linb = d_in[19];
  const void* lng  = d_in[20],*lnb  = d_in[21];

  auto run = [&](int b0, int nb){
    WSP w = mkws((char*)d_ws, nb);
    hipMemsetAsync(w.cnt, 0, (size_t)nb*N*4, stream);
    // CSR build (shared by all three convs)
    k_hist   <<<dim3(E/256,1,nb),   256,0,stream>>>(ei, w.cnt, b0);
    k_scan   <<<dim3(1,1,nb),       256,0,stream>>>(w.cnt, w.rowptr, w.cursor);
    k_scatter<<<dim3(E/256,1,nb),   256,0,stream>>>(ei, w.cursor, w.csr, b0);
    // conv1
    k_node1  <<<dim3(N/NT,1,nb),    256,0,stream>>>(x, c1Wl, c1Wr, w.xl1, w.xr1, w.flag, b0);
    k_pack1  <<<dim3(N*64/256,1,nb),256,0,stream>>>(w.xl1, w.xr1, w.xl1p, w.xr1p);
    k_gather1<<<dim3(N/4,1,nb),     256,0,stream>>>(w.rowptr, w.csr, ea, c1We, c1att, c1b,
                                                    w.xl1p, w.xr1p, w.hx, w.flag, b0);
    // conv2 + skip-conv
    k_node2  <<<dim3(N/NT,1,nb),    256,0,stream>>>(w.hx, w.xl1, c2Wl, c2Wr, sWl, sWr,
                                                    w.xl2, w.xr2, w.xl3, w.xr3, w.flag, b0);
    k_pack2  <<<dim3(N*16/256,1,nb),256,0,stream>>>(w.xl2, w.xr2, w.xl3, w.xr3, w.xl23p, w.xr23p);
    k_gather23<<<dim3(N/8,1,nb),    256,0,stream>>>(w.rowptr, w.csr, ea, c2We, sWe, c2att, satt,
                                                    c2b, sb, linW, linb, lng, lnb,
                                                    w.xl23p, w.xr23p, d_out, w.flag, b0);
  };

  {
    WSP w0 = mkws((char*)d_ws, 1);
    k_detect<<<1,256,0,stream>>>((const unsigned short*)x, w0.flag);
  }

  WSP probe = mkws((char*)0, NB_B);
  if (ws_size >= probe.total){
    run(0, NB_B);                          // single batched pass
  } else {
    for (int g=0; g<NB_B; ++g) run(g, 1);  // per-graph fallback
  }
}